// Round 3
// baseline (109.976 us; speedup 1.0000x reference)
//
#include <hip/hip_runtime.h>
#include <math.h>

// B=8, N=128, H2=800, FD=500, P=100
#define FD 500
#define H2 800
#define NRR 1024          // rows = 8*128
#define NPAD 2048         // padded feature cols (2000 real)
#define NKS 25            // 800 / 32

#define NEG_HUGE (-1.0e30f)  // stands in for -inf (ref has -inf -> threshold inf)

typedef __bf16 bf16x8 __attribute__((ext_vector_type(8)));
typedef float f32x4 __attribute__((ext_vector_type(4)));

union ChunkU { uint4 u; bf16x8 b; __bf16 h[8]; };

__device__ __forceinline__ float fast_tanh(float x) {
    float e = __expf(2.0f * x);
    return 1.0f - 2.0f / (e + 1.0f);
}

__device__ __forceinline__ bf16x8 as_frag(uint4 v) { ChunkU c; c.u = v; return c.b; }

// ---------------------------------------------------------------------------
// Kernel 1: selector vectors (8 x 500, stride 512) and 3 scalar constants
//  sel0=vg(grd->gk) sel1=vgh(head->gj) sel2=vgm(mod->gi)
//  sel3=vsh(head->sk) sel4=vss(sib->sj) sel5=vsm(mod->si)
//  sel6=vrh(head->r0) sel7=vrm(mod->ri);  consts: {c_g, c_s, c_r}
// ---------------------------------------------------------------------------
__global__ void prep_kernel(const float* __restrict__ W_gp, const float* __restrict__ b_gp,
                            const float* __restrict__ W_sp, const float* __restrict__ b_sp,
                            const float* __restrict__ W_rp, const float* __restrict__ b_rp,
                            const float* __restrict__ w_go, const float* __restrict__ b_go,
                            const float* __restrict__ w_so, const float* __restrict__ b_so,
                            float* __restrict__ sel, float* __restrict__ consts) {
    int v = blockIdx.x;
    int f = threadIdx.x;
    const float* wvec; const float* mat; int cols; int off;
    if (v < 3)      { wvec = w_go; mat = W_gp; cols = 3*FD; off = v*FD; }
    else if (v < 6) { wvec = w_so; mat = W_sp; cols = 3*FD; off = (v-3)*FD; }
    else            { wvec = w_go; mat = W_rp; cols = 2*FD; off = (v-6)*FD; }
    if (f < FD) {
        float s = 0.f;
        #pragma unroll 4
        for (int p = 0; p < 100; ++p) s += wvec[p] * mat[p*cols + off + f];
        sel[v*512 + f] = s;
    }
    if (v == 0 && f >= FD && f < FD+3) {
        int which = f - FD;
        const float* bv; const float* wv; float badd;
        if (which == 0)      { bv = b_gp; wv = w_go; badd = b_go[0]; }
        else if (which == 1) { bv = b_sp; wv = w_so; badd = b_so[0]; }
        else                 { bv = b_rp; wv = w_go; badd = b_go[0]; }
        float s = badd;
        for (int p = 0; p < 100; ++p) s += bv[p] * wv[p];
        consts[which] = s;
    }
}

// ---------------------------------------------------------------------------
// Kernel 2: build S8[8][2048] (selector-per-column matrix) and bias_c[2048]
// ---------------------------------------------------------------------------
__global__ void prep2_kernel(const float* __restrict__ sel,
                             const float* __restrict__ bh, const float* __restrict__ bm,
                             const float* __restrict__ bs, const float* __restrict__ bg,
                             float* __restrict__ S8, float* __restrict__ bias_c) {
    int c = blockIdx.x * 256 + threadIdx.x;   // 0..2047
    float v[8] = {0,0,0,0,0,0,0,0};
    float bias = 0.f;
    if (c < 2000) {
        int t = c / FD, f = c % FD;
        if (t == 0)      { v[1]=sel[1*512+f]; v[5]=sel[3*512+f]; v[7]=sel[6*512+f]; bias=bh[f]; }
        else if (t == 1) { v[0]=sel[2*512+f]; v[3]=sel[5*512+f]; v[6]=sel[7*512+f]; bias=bm[f]; }
        else if (t == 2) { v[4]=sel[4*512+f]; bias=bs[f]; }
        else             { v[2]=sel[0*512+f]; bias=bg[f]; }
    }
    #pragma unroll
    for (int q = 0; q < 8; ++q) S8[q*NPAD + c] = v[q];
    bias_c[c] = bias;
}

// ---------------------------------------------------------------------------
// Kernel 3: convert f32 -> bf16 hi/lo, pre-tiled in MFMA-fragment-linear order.
//  Tile (rb/cb, ks) = 512 uint4 chunks; chunk (h,f,l) holds
//  M[row = f*16 + (l&15)][k = ks*32 + (l>>4)*8 .. +7] (hi for h=0, lo for h=1).
//  A: 16 row-blocks; B: 32 col-blocks (cols >= 2000 zero-filled).
// ---------------------------------------------------------------------------
__global__ __launch_bounds__(256) void convert_kernel(
        const float* __restrict__ hidden,
        const float* __restrict__ Wh, const float* __restrict__ Wm,
        const float* __restrict__ Ws, const float* __restrict__ Wg,
        uint4* __restrict__ A_t, uint4* __restrict__ B_t) {
    int gid = blockIdx.x * 256 + threadIdx.x;   // 0 .. 307199
    const float* src = nullptr;
    uint4* dst;
    int l, f;
    if (gid < 102400) {          // A region: 16 rb * 25 ks * 4 f * 64 l
        l = gid & 63; f = (gid >> 6) & 3;
        int rest = gid >> 8;                // 0..399
        int ks = rest % NKS, rb = rest / NKS;
        int row = rb*64 + f*16 + (l & 15);
        int k0 = ks*32 + (l >> 4)*8;
        src = hidden + (size_t)row * H2 + k0;
        dst = A_t + (size_t)(rb*NKS + ks) * 512;
    } else {                     // B region: 32 cb * 25 ks * 4 f * 64 l
        int g2 = gid - 102400;
        l = g2 & 63; f = (g2 >> 6) & 3;
        int rest = g2 >> 8;                 // 0..799
        int ks = rest % NKS, cb = rest / NKS;
        int c = cb*64 + f*16 + (l & 15);
        int k0 = ks*32 + (l >> 4)*8;
        if (c < 2000) {
            int wt = c / FD, wf = c % FD;
            const float* wm = (wt==0)?Wh:(wt==1)?Wm:(wt==2)?Ws:Wg;
            src = wm + (size_t)wf * H2 + k0;
        }
        dst = B_t + (size_t)(cb*NKS + ks) * 512;
    }
    float x[8] = {0,0,0,0,0,0,0,0};
    if (src) {
        float4 v0 = *(const float4*)src;
        float4 v1 = *(const float4*)(src + 4);
        x[0]=v0.x; x[1]=v0.y; x[2]=v0.z; x[3]=v0.w;
        x[4]=v1.x; x[5]=v1.y; x[6]=v1.z; x[7]=v1.w;
    }
    ChunkU hc, lo;
    #pragma unroll
    for (int j = 0; j < 8; ++j) {
        __bf16 h = (__bf16)x[j];
        hc.h[j] = h;
        lo.h[j] = (__bf16)(x[j] - (float)h);
    }
    dst[(0*4 + f)*64 + l] = hc.u;
    dst[(1*4 + f)*64 + l] = lo.u;
}

// ---------------------------------------------------------------------------
// Kernel 4: MFMA GEMM (bf16 2-term split, 3 products) + fused tanh + selector
//  reduction. Block tile 64x64, 4 waves (each 32x32 = 2x2 frags of 16x16),
//  KS=32, double-buffered LDS, fragment-linear chunks (conflict-free b128).
//  Epilogue: y = tanh(acc+bias) -> LDS Y[64][64] -> partial rowvals per block.
// ---------------------------------------------------------------------------
__global__ __launch_bounds__(256, 2) void gemm_kernel(
        const uint4* __restrict__ A_t, const uint4* __restrict__ B_t,
        const float* __restrict__ S8, const float* __restrict__ bias_c,
        float* __restrict__ partials) {
    __shared__ uint4 Abuf[2][512];
    __shared__ uint4 Bbuf[2][512];
    int tid = threadIdx.x;
    int cb = blockIdx.x;    // 0..31
    int rb = blockIdx.y;    // 0..15
    int l  = tid & 63;
    int wid = tid >> 6;
    int wr = wid >> 1, wc = wid & 1;

    const uint4* Ablk = A_t + (size_t)rb * NKS * 512;
    const uint4* Bblk = B_t + (size_t)cb * NKS * 512;

    uint4 st[4];
    // staging: threads 0-127 handle A chunks {t, t+128, t+256, t+384}; 128-255 B.
    #define STAGE_LOAD(ks) do { \
        const uint4* s_ = (tid < 128) ? (Ablk + (ks)*512 + tid) : (Bblk + (ks)*512 + (tid-128)); \
        st[0]=s_[0]; st[1]=s_[128]; st[2]=s_[256]; st[3]=s_[384]; } while(0)
    #define STAGE_WRITE(buf) do { \
        uint4* d_ = (tid < 128) ? &Abuf[buf][tid] : &Bbuf[buf][tid-128]; \
        d_[0]=st[0]; d_[128]=st[1]; d_[256]=st[2]; d_[384]=st[3]; } while(0)

    f32x4 acc[2][2];
    #pragma unroll
    for (int m=0;m<2;++m)
        #pragma unroll
        for (int n=0;n<2;++n) acc[m][n] = (f32x4){0.f,0.f,0.f,0.f};

    STAGE_LOAD(0); STAGE_WRITE(0);
    __syncthreads();
    STAGE_LOAD(1);

    for (int ks = 0; ks < NKS; ++ks) {
        int cur = ks & 1;
        int fa = wr*2, fb = wc*2;
        bf16x8 a_h[2], a_l[2], b_h[2], b_l[2];
        #pragma unroll
        for (int m=0;m<2;++m) {
            a_h[m] = as_frag(Abuf[cur][(0 + fa + m)*64 + l]);
            a_l[m] = as_frag(Abuf[cur][(4 + fa + m)*64 + l]);
        }
        #pragma unroll
        for (int n=0;n<2;++n) {
            b_h[n] = as_frag(Bbuf[cur][(0 + fb + n)*64 + l]);
            b_l[n] = as_frag(Bbuf[cur][(4 + fb + n)*64 + l]);
        }
        #pragma unroll
        for (int m=0;m<2;++m)
            #pragma unroll
            for (int n=0;n<2;++n) {
                acc[m][n] = __builtin_amdgcn_mfma_f32_16x16x32_bf16(a_h[m], b_h[n], acc[m][n], 0,0,0);
                acc[m][n] = __builtin_amdgcn_mfma_f32_16x16x32_bf16(a_h[m], b_l[n], acc[m][n], 0,0,0);
                acc[m][n] = __builtin_amdgcn_mfma_f32_16x16x32_bf16(a_l[m], b_h[n], acc[m][n], 0,0,0);
            }
        if (ks + 1 < NKS) {
            __syncthreads();               // everyone done reading buf[(ks+1)&1]
            STAGE_WRITE((ks+1) & 1);       // compiler waits vmcnt for st regs
            __syncthreads();               // tile ks+1 visible
            if (ks + 2 < NKS) STAGE_LOAD(ks+2);   // issue next loads (hidden under compute)
        }
    }

    // ---- epilogue: tanh + bias into LDS Y[64][64], then selector reduce ----
    int lr = l >> 4, lc = l & 15;
    __syncthreads();                       // all waves done with Abuf
    float* Y = (float*)Abuf;               // 16 KB = 64*64 f32
    #pragma unroll
    for (int n=0;n<2;++n) {
        int col_local = (wc*2 + n)*16 + lc;
        float bias = bias_c[cb*64 + col_local];
        #pragma unroll
        for (int m=0;m<2;++m) {
            int row_base = (wr*2 + m)*16 + lr*4;
            #pragma unroll
            for (int r=0;r<4;++r)
                Y[(row_base + r)*64 + col_local] = fast_tanh(acc[m][n][r] + bias);
        }
    }
    __syncthreads();
    // 512 tasks = 64 rows x 8 q; each thread 2 tasks
    #pragma unroll
    for (int it=0; it<2; ++it) {
        int task = tid + it*256;
        int q = task & 7, row = task >> 3;
        const float* s8r = S8 + q*NPAD + cb*64;
        const float* yr = Y + row*64;
        float s = 0.f;
        #pragma unroll 8
        for (int c2=0;c2<64;++c2) s += yr[c2] * s8r[c2];
        partials[((size_t)cb*NRR + rb*64 + row)*8 + q] = s;
    }
    #undef STAGE_LOAD
    #undef STAGE_WRITE
}

// ---------------------------------------------------------------------------
// Kernel 5: rowvals[r][q] = sum over 32 col-blocks of partials
// ---------------------------------------------------------------------------
__global__ void finish_kernel(const float* __restrict__ partials,
                              float* __restrict__ rowvals) {
    int t = blockIdx.x*256 + threadIdx.x;   // 0..8191 = row*8 + q
    float s = 0.f;
    #pragma unroll 8
    for (int cbk = 0; cbk < 32; ++cbk) s += partials[(size_t)cbk*8192 + t];
    rowvals[t] = s;
}

// ---------------------------------------------------------------------------
// Kernel 6: fill both (B,N,N,N) outputs.
// ---------------------------------------------------------------------------
#define KSPLIT 2
__global__ __launch_bounds__(256) void fill_kernel(
        const float* __restrict__ rowvals, const float* __restrict__ consts,
        float* __restrict__ grand, float* __restrict__ sib) {
    int bi = blockIdx.x;          // b*128 + i
    int kz = blockIdx.y;
    int b = bi >> 7;
    int i = bi & 127;
    int tid = threadIdx.x;

    __shared__ float gks[128], gjs[128], sks[128], sjs[128];
    if (tid < 128) {
        const float* rv = rowvals + (size_t)(b*128 + tid)*8;
        gks[tid] = rv[2];
        gjs[tid] = rv[1];
        sks[tid] = rv[5];
        sjs[tid] = rv[4];
    }
    __syncthreads();

    const float* rvi = rowvals + (size_t)bi * 8;
    float gi = rvi[0], si = rvi[3];
    float c_g = consts[0], c_s = consts[1], c_r = consts[2];
    float r0 = rowvals[(size_t)(b*128)*8 + 7];
    float ri = rvi[6];
    float rootv = fast_tanh(r0 + ri + c_r);

    size_t base = (size_t)bi * (128*128);

    int j4 = (tid & 31) * 4;
    int klo = tid >> 5;                  // 0..7
    const int KROWS = 128 / KSPLIT;      // 64

    for (int it = 0; it < KROWS/8; ++it) {
        int k = kz*KROWS + it*8 + klo;
        float gk = gks[k], sk = sks[k];
        float4 go, so;
        #pragma unroll
        for (int jj = 0; jj < 4; ++jj) {
            int j = j4 + jj;
            bool valid = (i != 0) && (i != j) && (j != k);
            float g = valid ? fast_tanh(gi + gk + gjs[j] + c_g) : NEG_HUGE;
            float s = valid ? fast_tanh(si + sk + sjs[j] + c_s) : 0.0f;
            if (i != 0 && k == 0 && j == 0) g = rootv;
            (&go.x)[jj] = g;
            (&so.x)[jj] = s;
        }
        size_t off = base + (size_t)k*128 + j4;
        *(float4*)(grand + off) = go;
        *(float4*)(sib + off) = so;
    }
}

// ---------------------------------------------------------------------------
extern "C" void kernel_launch(void* const* d_in, const int* in_sizes, int n_in,
                              void* d_out, int out_size, void* d_ws, size_t ws_size,
                              hipStream_t stream) {
    const float* hidden = (const float*)d_in[0];
    const float* Wh  = (const float*)d_in[1];   const float* bh  = (const float*)d_in[2];
    const float* Wm  = (const float*)d_in[3];   const float* bm  = (const float*)d_in[4];
    const float* Ws_ = (const float*)d_in[5];   const float* bs  = (const float*)d_in[6];
    const float* Wg  = (const float*)d_in[7];   const float* bg  = (const float*)d_in[8];
    const float* W_gp = (const float*)d_in[9];  const float* b_gp = (const float*)d_in[10];
    const float* W_sp = (const float*)d_in[11]; const float* b_sp = (const float*)d_in[12];
    const float* W_rp = (const float*)d_in[13]; const float* b_rp = (const float*)d_in[14];
    const float* w_go = (const float*)d_in[15]; const float* b_go = (const float*)d_in[16];
    const float* w_so = (const float*)d_in[17]; const float* b_so = (const float*)d_in[18];

    float* out   = (float*)d_out;
    float* grand = out;                        // 16777216 floats
    float* sib   = out + (size_t)16777216;     // 16777216 floats

    // bf16 tiled scratch lives in the grand half of d_out (consumed by gemm,
    // overwritten by fill which runs last in stream order).
    uint4* A_t = (uint4*)out;                  // 16*25*512   = 204800 uint4 (3.28 MB)
    uint4* B_t = (uint4*)out + 204800;         // 32*25*512   = 409600 uint4 (6.55 MB)

    // small scratch in d_ws (~1.2 MB)
    float* S8      = (float*)d_ws;             // 8*2048 = 16384
    float* bias_c  = S8 + 16384;               // 2048
    float* sel     = bias_c + 2048;            // 8*512 = 4096
    float* consts  = sel + 4096;               // 16
    float* rowvals = consts + 16;              // 8192
    float* partials= rowvals + 8192;           // 32*1024*8 = 262144

    prep_kernel<<<dim3(8), dim3(512), 0, stream>>>(W_gp, b_gp, W_sp, b_sp, W_rp, b_rp,
                                                   w_go, b_go, w_so, b_so, sel, consts);
    prep2_kernel<<<dim3(8), dim3(256), 0, stream>>>(sel, bh, bm, bs, bg, S8, bias_c);
    convert_kernel<<<dim3(1200), dim3(256), 0, stream>>>(hidden, Wh, Wm, Ws_, Wg, A_t, B_t);
    gemm_kernel<<<dim3(32,16), dim3(256), 0, stream>>>(A_t, B_t, S8, bias_c, partials);
    finish_kernel<<<dim3(32), dim3(256), 0, stream>>>(partials, rowvals);
    fill_kernel<<<dim3(1024, KSPLIT), dim3(256), 0, stream>>>(rowvals, consts, grand, sib);
}